// Round 1
// baseline (1857.502 us; speedup 1.0000x reference)
//
#include <hip/hip_runtime.h>

#define N_NODES 100000
#define N_EDGES 1600000
#define E_TOT   (N_EDGES + N_NODES)
#define NPART   8
#define PART_SZ (N_NODES / NPART)   // 12500
#define CAP 48                      // bucket capacity; degree ~ Poisson(16), P(>=48) ~ 1e-9
#define SCAP 32768                  // staging sublist capacity (mean 26.6k, sigma ~152)
#define SSH  15                     // log2(SCAP)

static __device__ __forceinline__ float lrelu(float z) { return z > 0.f ? z : 0.2f * z; }

// bf16 round-to-nearest-even pack / unpack (values are finite, no NaN handling)
static __device__ __forceinline__ unsigned f2bf(float f) {
    unsigned u = __float_as_uint(f);
    u += 0x7fffu + ((u >> 16) & 1u);
    return u >> 16;
}
static __device__ __forceinline__ float bf_lo(unsigned v) { return __uint_as_float(v << 16); }
static __device__ __forceinline__ float bf_hi(unsigned v) { return __uint_as_float(v & 0xffff0000u); }

// ---------------- phase A: single-pass edge binning into per-(part,stripe) staging ----------------
// Round-11 pathology: the 8-XCD dst-range design re-scanned the full dst stream 8x
// (FETCH 50 MB) with NT (L2-bypass) dependent loads -> latency-bound at 19% BW, 78 us.
// Fix: read each edge ONCE, pack (dst_local 14b | src 17b) into a u32, append to
// stage[part][stripe] via wave-ballot aggregation (one atomic per part per wave into
// a 64-counter tail array -> no same-address hot-spot; slots consecutive -> stores coalesce).
__global__ __launch_bounds__(256) void bucket_build(const int* __restrict__ ei, int* __restrict__ tails,
                                                    unsigned* __restrict__ stage) {
    int stripe = blockIdx.x & 7;            // contention-spreading stripe (~XCD round-robin)
    int lane = threadIdx.x & 63;
    unsigned long long lt = (1ull << lane) - 1ull;
    int t0 = blockIdx.x * 256 + threadIdx.x;
#pragma unroll
    for (int k = 0; k < 4; ++k) {           // 4 * 524288 threads covers E_TOT = 1.7M
        int t = t0 + k * (2048 * 256);
        bool valid = t < E_TOT;
        int d = 0, s = 0;
        if (valid) {
            if (t < N_EDGES) {
                d = __builtin_nontemporal_load(ei + N_EDGES + t);
                s = __builtin_nontemporal_load(ei + t);
            } else {                        // self-loop
                d = t - N_EDGES; s = d;
            }
        }
        int part = (int)((unsigned)d / PART_SZ);
        unsigned v = ((unsigned)(d - part * PART_SZ) << 17) | (unsigned)s;  // 14b | 17b
#pragma unroll
        for (int p = 0; p < NPART; ++p) {
            unsigned long long m = __ballot(valid && part == p);
            if (m == 0ull) continue;        // wave-uniform
            int leader = (int)__builtin_ctzll(m);
            int base = 0;
            if (lane == leader) base = atomicAdd(&tails[p * 8 + stripe], (int)__popcll(m));
            base = __shfl(base, leader);
            if (valid && part == p) {
                int slot = base + (int)__popcll(m & lt);
                if (slot < SCAP) stage[(((p << 3) | stripe) << SSH) + slot] = v;
            }
        }
    }
}

// ---------------- phase B: XCD-local scatter from staging into CSR buckets ----------------
// blockIdx&7 = part -> each XCD streams its own contiguous staging sublists (NT, read once)
// and scatters into its 2.4 MB bucket slice + 50 KB cnt slice, which stay L2-resident
// with no competing stream traffic -> each bucket line written back once.
__global__ __launch_bounds__(256) void bucket_fill(const int* __restrict__ tails, const unsigned* __restrict__ stage,
                                                   int* __restrict__ cnt, int* __restrict__ srcs) {
    int part = blockIdx.x & 7;
    int sub = blockIdx.x >> 3;              // 0..255
    int stripe = sub & 7;
    int blk = sub >> 3;                     // 0..31 blocks per (part,stripe)
    int len = tails[part * 8 + stripe];
    if (len > SCAP) len = SCAP;
    int lo = part * PART_SZ;
    const unsigned* sl = stage + (((part << 3) | stripe) << SSH);
    for (int i = blk * 256 + (int)threadIdx.x; i < len; i += 32 * 256) {
        unsigned v = __builtin_nontemporal_load(sl + i);
        int d = lo + (int)(v >> 17);
        int s = (int)(v & 0x1FFFFu);
        int slot = atomicAdd(&cnt[d], 1);
        if (slot < CAP) srcs[d * CAP + slot] = s;
    }
}

// ---------------- fused GEMM + attention logits (wave-sliced, scalar W path) ----------------
// readfirstlane forces the W address chain into SGPRs -> s_load per k-row (round-6 win).
// h written as bf16 (round-9 win: halves gather traffic downstream).
template <int IN, int OUT, int HEADS, int NPB>
__global__ __launch_bounds__(256) void gemm_al(const float* __restrict__ x, const float* __restrict__ W,
                                               const float* __restrict__ asrc, const float* __restrict__ adst,
                                               unsigned short* __restrict__ h, float* __restrict__ als,
                                               float* __restrict__ ald) {
    constexpr int SPLIT = OUT / 16;
    constexpr int STRIDE = IN + 1;
    constexpr int F4PT = NPB * (IN / 4) / 256;
    __shared__ float sx[NPB * STRIDE];
    int t = threadIdx.x;
    long base = (long)blockIdx.x * NPB;

#pragma unroll
    for (int p = 0; p < F4PT; ++p) {
        int e = p * 256 + t;
        int row = e / (IN / 4);
        int c4 = e % (IN / 4);
        long gr = base + row;
        if (gr >= N_NODES) gr = N_NODES - 1;
        float4 v = *reinterpret_cast<const float4*>(&x[gr * IN + c4 * 4]);
        float* d = &sx[row * STRIDE + c4 * 4];
        d[0] = v.x; d[1] = v.y; d[2] = v.z; d[3] = v.w;
    }
    __syncthreads();

    int w = t >> 6, lane = t & 63;
    int s = __builtin_amdgcn_readfirstlane(w % SPLIT);
    int grp = __builtin_amdgcn_readfirstlane(w / SPLIT);
    int r = grp * 64 + lane;
    long n = base + r;

    float acc[16];
#pragma unroll
    for (int j = 0; j < 16; ++j) acc[j] = 0.f;

    const float* Ws = W + s * 16;
#pragma unroll 8
    for (int k = 0; k < IN; ++k) {
        float xv = sx[r * STRIDE + k];
        const float* Wr = Ws + k * OUT;
#pragma unroll
        for (int j = 0; j < 16; ++j) acc[j] = fmaf(xv, Wr[j], acc[j]);
    }

    if (n < N_NODES) {
        unsigned u[8];
#pragma unroll
        for (int k = 0; k < 8; ++k)
            u[k] = f2bf(acc[2 * k]) | (f2bf(acc[2 * k + 1]) << 16);
        uint4* dst = reinterpret_cast<uint4*>(&h[n * OUT + s * 16]);
        dst[0] = make_uint4(u[0], u[1], u[2], u[3]);
        dst[1] = make_uint4(u[4], u[5], u[6], u[7]);
    }

    float ps = 0.f, pd = 0.f;
#pragma unroll
    for (int j = 0; j < 16; ++j) {
        ps = fmaf(acc[j], asrc[s * 16 + j], ps);
        pd = fmaf(acc[j], adst[s * 16 + j], pd);
    }
    if (HEADS == SPLIT) {
        if (n < N_NODES) {
            als[n * HEADS + s] = ps;
            ald[n * HEADS + s] = pd;
        }
    } else {
        __syncthreads();
        sx[r * 2 + s] = ps;
        sx[NPB * 2 + r * 2 + s] = pd;
        __syncthreads();
        if (t < NPB) {
            long nn = base + t;
            if (nn < N_NODES) {
                als[nn] = sx[t * 2] + sx[t * 2 + 1];
                ald[nn] = sx[NPB * 2 + t * 2] + sx[NPB * 2 + t * 2 + 1];
            }
        }
    }
}

// XCD-aligned node mapping for agg: XCD k (blockIdx&7) processes dst range k.
static __device__ __forceinline__ int agg_node(int blk, int wid) {
    return (blk & 7) * PART_SZ + (blk >> 3) * 4 + wid;
}

// ---------------- aggregation, H=4 C=16, bf16 payload, uint4 lanes ----------------
// bf16 row = 128 B = 8 lanes x uint4 -> q=lane>>3 gives 8 edges in flight.
__global__ __launch_bounds__(256) void agg_h4(const int* __restrict__ cnt, const int* __restrict__ srcs,
                                              const unsigned short* __restrict__ h, const float* __restrict__ als,
                                              const float* __restrict__ ald, const float* __restrict__ bias,
                                              float* __restrict__ g, int do_relu) {
    const uint4* hrow = reinterpret_cast<const uint4*>(h);   // 8 uint4 per 64-ch row
    int wid = threadIdx.x >> 6, lane = threadIdx.x & 63;
    int n = agg_node(blockIdx.x, wid);
    if (n >= N_NODES) return;
    int q = lane >> 3, cc = lane & 7;
    int hd = cc >> 1;
    float ad = ald[n * 4 + hd];
    int deg = cnt[n]; if (deg > CAP) deg = CAP;   // deg >= 1 (self-loop)
    int e0 = n * CAP, e1 = e0 + deg;
    float a0 = 0.f, a1 = 0.f, a2 = 0.f, a3 = 0.f, a4 = 0.f, a5 = 0.f, a6 = 0.f, a7 = 0.f;
    float den = 0.f;

    int idxA = e0 + q; if (idxA >= e1) idxA = e1 - 1;
    int sA = srcs[idxA];
    float alA = als[sA * 4 + hd];
    uint4 hvA = hrow[(long)sA * 8 + cc];
    bool mA = (e0 + q) < e1;

    for (int e = e0; e < e1; e += 8) {
        int eB = e + 8;
        int sB = sA; float alB = alA; uint4 hvB = hvA; bool mB = mA;
        if (eB < e1) {                    // wave-uniform branch
            int idxB = eB + q; if (idxB >= e1) idxB = e1 - 1;
            sB = srcs[idxB];
            alB = als[sB * 4 + hd];
            hvB = hrow[(long)sB * 8 + cc];
            mB = (eB + q) < e1;
        }
        float w = mA ? __expf(lrelu(alA + ad)) : 0.f;
        den += w;
        a0 = fmaf(w, bf_lo(hvA.x), a0);
        a1 = fmaf(w, bf_hi(hvA.x), a1);
        a2 = fmaf(w, bf_lo(hvA.y), a2);
        a3 = fmaf(w, bf_hi(hvA.y), a3);
        a4 = fmaf(w, bf_lo(hvA.z), a4);
        a5 = fmaf(w, bf_hi(hvA.z), a5);
        a6 = fmaf(w, bf_lo(hvA.w), a6);
        a7 = fmaf(w, bf_hi(hvA.w), a7);
        sA = sB; alA = alB; hvA = hvB; mA = mB;
    }

#pragma unroll
    for (int d = 8; d <= 32; d <<= 1) {
        a0 += __shfl_xor(a0, d); a1 += __shfl_xor(a1, d);
        a2 += __shfl_xor(a2, d); a3 += __shfl_xor(a3, d);
        a4 += __shfl_xor(a4, d); a5 += __shfl_xor(a5, d);
        a6 += __shfl_xor(a6, d); a7 += __shfl_xor(a7, d);
        den += __shfl_xor(den, d);
    }
    if (q == 0) {
        float4 b0 = *reinterpret_cast<const float4*>(&bias[cc * 8]);
        float4 b1 = *reinterpret_cast<const float4*>(&bias[cc * 8 + 4]);
        float inv = 1.f / den;
        float4 o0, o1;
        o0.x = fmaf(a0, inv, b0.x); o0.y = fmaf(a1, inv, b0.y);
        o0.z = fmaf(a2, inv, b0.z); o0.w = fmaf(a3, inv, b0.w);
        o1.x = fmaf(a4, inv, b1.x); o1.y = fmaf(a5, inv, b1.y);
        o1.z = fmaf(a6, inv, b1.z); o1.w = fmaf(a7, inv, b1.w);
        if (do_relu) {
            o0.x = fmaxf(o0.x, 0.f); o0.y = fmaxf(o0.y, 0.f);
            o0.z = fmaxf(o0.z, 0.f); o0.w = fmaxf(o0.w, 0.f);
            o1.x = fmaxf(o1.x, 0.f); o1.y = fmaxf(o1.y, 0.f);
            o1.z = fmaxf(o1.z, 0.f); o1.w = fmaxf(o1.w, 0.f);
        }
        *reinterpret_cast<float4*>(&g[(long)n * 64 + cc * 8]) = o0;
        *reinterpret_cast<float4*>(&g[(long)n * 64 + cc * 8 + 4]) = o1;
    }
}

// ---------------- aggregation, H=1 C=32, bf16 payload, uint4 lanes ----------------
// 32-ch bf16 row = 64 B = 4 lanes x uint4 -> q=lane>>2 gives 16 edges in flight.
__global__ __launch_bounds__(256) void agg_h1(const int* __restrict__ cnt, const int* __restrict__ srcs,
                                              const unsigned short* __restrict__ h3, const float* __restrict__ als,
                                              const float* __restrict__ ald, const float* __restrict__ bias,
                                              float* __restrict__ out) {
    const uint4* hrow = reinterpret_cast<const uint4*>(h3);  // 4 uint4 per 32-ch row
    int wid = threadIdx.x >> 6, lane = threadIdx.x & 63;
    int n = agg_node(blockIdx.x, wid);
    if (n >= N_NODES) return;
    int q = lane >> 2, cc = lane & 3;
    float ad = ald[n];
    int deg = cnt[n]; if (deg > CAP) deg = CAP;
    int e0 = n * CAP, e1 = e0 + deg;
    float a0 = 0.f, a1 = 0.f, a2 = 0.f, a3 = 0.f, a4 = 0.f, a5 = 0.f, a6 = 0.f, a7 = 0.f;
    float den = 0.f;

    int idxA = e0 + q; if (idxA >= e1) idxA = e1 - 1;
    int sA = srcs[idxA];
    float alA = als[sA];
    uint4 hvA = hrow[(long)sA * 4 + cc];
    bool mA = (e0 + q) < e1;

    for (int e = e0; e < e1; e += 16) {
        int eB = e + 16;
        int sB = sA; float alB = alA; uint4 hvB = hvA; bool mB = mA;
        if (eB < e1) {
            int idxB = eB + q; if (idxB >= e1) idxB = e1 - 1;
            sB = srcs[idxB];
            alB = als[sB];
            hvB = hrow[(long)sB * 4 + cc];
            mB = (eB + q) < e1;
        }
        float w = mA ? __expf(lrelu(alA + ad)) : 0.f;
        den += w;
        a0 = fmaf(w, bf_lo(hvA.x), a0);
        a1 = fmaf(w, bf_hi(hvA.x), a1);
        a2 = fmaf(w, bf_lo(hvA.y), a2);
        a3 = fmaf(w, bf_hi(hvA.y), a3);
        a4 = fmaf(w, bf_lo(hvA.z), a4);
        a5 = fmaf(w, bf_hi(hvA.z), a5);
        a6 = fmaf(w, bf_lo(hvA.w), a6);
        a7 = fmaf(w, bf_hi(hvA.w), a7);
        sA = sB; alA = alB; hvA = hvB; mA = mB;
    }

#pragma unroll
    for (int d = 4; d <= 32; d <<= 1) {
        a0 += __shfl_xor(a0, d); a1 += __shfl_xor(a1, d);
        a2 += __shfl_xor(a2, d); a3 += __shfl_xor(a3, d);
        a4 += __shfl_xor(a4, d); a5 += __shfl_xor(a5, d);
        a6 += __shfl_xor(a6, d); a7 += __shfl_xor(a7, d);
        den += __shfl_xor(den, d);
    }
    if (q == 0) {
        float4 b0 = *reinterpret_cast<const float4*>(&bias[cc * 8]);
        float4 b1 = *reinterpret_cast<const float4*>(&bias[cc * 8 + 4]);
        float inv = 1.f / den;
        float4 o0, o1;
        o0.x = fmaf(a0, inv, b0.x); o0.y = fmaf(a1, inv, b0.y);
        o0.z = fmaf(a2, inv, b0.z); o0.w = fmaf(a3, inv, b0.w);
        o1.x = fmaf(a4, inv, b1.x); o1.y = fmaf(a5, inv, b1.y);
        o1.z = fmaf(a6, inv, b1.z); o1.w = fmaf(a7, inv, b1.w);
        *reinterpret_cast<float4*>(&out[(long)n * 32 + cc * 8]) = o0;
        *reinterpret_cast<float4*>(&out[(long)n * 32 + cc * 8 + 4]) = o1;
    }
}

extern "C" void kernel_launch(void* const* d_in, const int* in_sizes, int n_in,
                              void* d_out, int out_size, void* d_ws, size_t ws_size,
                              hipStream_t stream) {
    (void)in_sizes; (void)n_in; (void)out_size; (void)ws_size;
    const float* x   = (const float*)d_in[0];
    const int*   ei  = (const int*)d_in[1];
    const float* W1  = (const float*)d_in[2];
    const float* as1 = (const float*)d_in[3];
    const float* ad1 = (const float*)d_in[4];
    const float* b1  = (const float*)d_in[5];
    const float* W2  = (const float*)d_in[6];
    const float* as2 = (const float*)d_in[7];
    const float* ad2 = (const float*)d_in[8];
    const float* b2  = (const float*)d_in[9];
    const float* W3  = (const float*)d_in[10];
    const float* as3 = (const float*)d_in[11];
    const float* ad3 = (const float*)d_in[12];
    const float* b3  = (const float*)d_in[13];
    float* out = (float*)d_out;

    char* w = (char*)d_ws;
    auto alloc = [&](size_t bytes) {
        void* p = (void*)w;
        w += (bytes + 255) & ~(size_t)255;
        return p;
    };
    int*            cnt   = (int*)alloc((size_t)N_NODES * 4);
    int*            tails = (int*)alloc((size_t)64 * 4);
    int*            srcs  = (int*)alloc((size_t)N_NODES * CAP * 4);   // 19.2 MB
    unsigned short* h     = (unsigned short*)alloc((size_t)N_NODES * 64 * 2);  // bf16, 12.8 MB
    float*          g     = (float*)alloc((size_t)N_NODES * 64 * 4);  // 25.6 MB
    float*          als   = (float*)alloc((size_t)N_NODES * 4 * 4);
    float*          ald   = (float*)alloc((size_t)N_NODES * 4 * 4);
    // staging (8 MB) aliases g: consumed by bucket_fill before agg_h4 first writes g.
    unsigned*       stage = (unsigned*)g;

    hipMemsetAsync(cnt, 0, (size_t)N_NODES * 4, stream);
    hipMemsetAsync(tails, 0, (size_t)64 * 4, stream);

    int g64  = (N_NODES + 63) / 64;    // 1563
    int g128 = (N_NODES + 127) / 128;  // 782
    int gAgg = ((N_NODES + 3) / 4 + 7) & ~7;   // 25000 -> mult of 8

    bucket_build<<<2048, 256, 0, stream>>>(ei, tails, stage);
    bucket_fill<<<2048, 256, 0, stream>>>(tails, stage, cnt, srcs);

    // layer 1: x[100000,128] @ W1[128,64], H=4
    gemm_al<128, 64, 4, 64><<<g64, 256, 0, stream>>>(x, W1, as1, ad1, h, als, ald);
    agg_h4<<<gAgg, 256, 0, stream>>>(cnt, srcs, h, als, ald, b1, g, 1);
    // layer 2: g[100000,64] @ W2[64,64], H=4
    gemm_al<64, 64, 4, 64><<<g64, 256, 0, stream>>>(g, W2, as2, ad2, h, als, ald);
    agg_h4<<<gAgg, 256, 0, stream>>>(cnt, srcs, h, als, ald, b2, g, 1);
    // layer 3: g[100000,64] @ W3[64,32], H=1 -> d_out
    gemm_al<64, 32, 1, 128><<<g128, 256, 0, stream>>>(g, W3, as3, ad3, h, als, ald);
    agg_h1<<<gAgg, 256, 0, stream>>>(cnt, srcs, h, als, ald, b3, out);
}

// Round 3
// 407.549 us; speedup vs baseline: 4.5577x; 4.5577x over previous
//
#include <hip/hip_runtime.h>

#define N_NODES 100000
#define N_EDGES 1600000
#define E_TOT   (N_EDGES + N_NODES)
#define NPART   8
#define PART_SZ (N_NODES / NPART)   // 12500
#define CAP 48                      // bucket capacity; degree ~ Poisson(16), P(>=48) ~ 1e-9
#define SCAP 32768                  // staging sublist capacity (mean 26.6k, sigma ~152)
#define SSH  15                     // log2(SCAP)
#define EPB  1024                   // edges per build block
#define BCAP EPB                    // per-block LDS bin cap == EPB: overflow IMPOSSIBLE even for
                                    // fully-skewed blocks (round-13 bug: self-loop tail is
                                    // SEQUENTIAL dst -> whole block lands in one partition;
                                    // BCAP=256 dropped ~3/4 of those self-loops)

static __device__ __forceinline__ float lrelu(float z) { return z > 0.f ? z : 0.2f * z; }

// bf16 round-to-nearest-even pack / unpack (values are finite, no NaN handling)
static __device__ __forceinline__ unsigned f2bf(float f) {
    unsigned u = __float_as_uint(f);
    u += 0x7fffu + ((u >> 16) & 1u);
    return u >> 16;
}
static __device__ __forceinline__ float bf_lo(unsigned v) { return __uint_as_float(v << 16); }
static __device__ __forceinline__ float bf_hi(unsigned v) { return __uint_as_float(v & 0xffff0000u); }

// ---------------- phase A: single-pass edge binning, block-local LDS bins ----------------
// Round-12 pathology: per-wave ballot reservation = 262K device-scope atomics onto a
// 256-B tails array (2 cache lines) -> cross-XCD same-line serialization = 1.5 ms.
// Fix: bin 1024 edges/block into LDS via LDS atomics (block-local, cheap), then reserve
// global space with ONE atomic per (block,partition) = 13.3K total, onto counters padded
// so each stripe's 8 counters own a 128-B line; stripe = blockIdx&7 ~ XCD id (round-robin
// dispatch) -> reservation atomics stay XCD-local. Flush = coalesced LDS->global copy.
__global__ __launch_bounds__(256) void bucket_build(const int* __restrict__ ei, int* __restrict__ tails,
                                                    unsigned* __restrict__ stage) {
    __shared__ unsigned bins[NPART][BCAP];   // 32 KB: total capacity == EPB, cannot overflow
    __shared__ int lcnt[NPART];
    __shared__ int lbase[NPART];
    int tid = threadIdx.x;
    if (tid < NPART) lcnt[tid] = 0;
    __syncthreads();

    int stripe = blockIdx.x & 7;
    int e0 = blockIdx.x * EPB;
#pragma unroll
    for (int k = 0; k < EPB / 256; ++k) {
        int t = e0 + k * 256 + tid;
        if (t < E_TOT) {
            int d, s;
            if (t < N_EDGES) {
                d = __builtin_nontemporal_load(ei + N_EDGES + t);
                s = __builtin_nontemporal_load(ei + t);
            } else {                        // self-loop (sequential d!)
                d = t - N_EDGES; s = d;
            }
            int part = (int)((unsigned)d / PART_SZ);
            unsigned v = ((unsigned)(d - part * PART_SZ) << 17) | (unsigned)s;  // 14b | 17b
            int slot = atomicAdd(&lcnt[part], 1);
            bins[part][slot] = v;           // slot < EPB == BCAP by construction
        }
    }
    __syncthreads();

    if (tid < NPART) {
        lbase[tid] = atomicAdd(&tails[(stripe << 5) + tid], lcnt[tid]);   // padded: 128 B per stripe
    }
    __syncthreads();

    int p = tid >> 5;                       // 32 threads per partition
    int c = lcnt[p];
    int gb = lbase[p];
    unsigned* dst = stage + (((p << 3) | stripe) << SSH);
    for (int i = tid & 31; i < c; i += 32) {
        int slot = gb + i;
        if (slot < SCAP) dst[slot] = bins[p][i];
    }
}

// ---------------- phase B: XCD-local scatter from staging into CSR buckets ----------------
// blockIdx&7 = part -> each XCD streams its own contiguous staging sublists (NT, read once)
// and scatters into its 2.4 MB bucket slice + 50 KB cnt slice, which stay L2-resident
// with no competing stream traffic -> each bucket line written back once. (~12 us, round-12)
__global__ __launch_bounds__(256) void bucket_fill(const int* __restrict__ tails, const unsigned* __restrict__ stage,
                                                   int* __restrict__ cnt, int* __restrict__ srcs) {
    int part = blockIdx.x & 7;
    int sub = blockIdx.x >> 3;              // 0..255
    int stripe = sub & 7;
    int blk = sub >> 3;                     // 0..31 blocks per (part,stripe)
    int len = tails[(stripe << 5) + part];
    if (len > SCAP) len = SCAP;
    int lo = part * PART_SZ;
    const unsigned* sl = stage + (((part << 3) | stripe) << SSH);
    for (int i = blk * 256 + (int)threadIdx.x; i < len; i += 32 * 256) {
        unsigned v = __builtin_nontemporal_load(sl + i);
        int d = lo + (int)(v >> 17);
        int s = (int)(v & 0x1FFFFu);
        int slot = atomicAdd(&cnt[d], 1);
        if (slot < CAP) srcs[d * CAP + slot] = s;
    }
}

// ---------------- fused GEMM + attention logits (wave-sliced, scalar W path) ----------------
// readfirstlane forces the W address chain into SGPRs -> s_load per k-row (round-6 win).
// h written as bf16 (round-9 win: halves gather traffic downstream).
template <int IN, int OUT, int HEADS, int NPB>
__global__ __launch_bounds__(256) void gemm_al(const float* __restrict__ x, const float* __restrict__ W,
                                               const float* __restrict__ asrc, const float* __restrict__ adst,
                                               unsigned short* __restrict__ h, float* __restrict__ als,
                                               float* __restrict__ ald) {
    constexpr int SPLIT = OUT / 16;
    constexpr int STRIDE = IN + 1;
    constexpr int F4PT = NPB * (IN / 4) / 256;
    __shared__ float sx[NPB * STRIDE];
    int t = threadIdx.x;
    long base = (long)blockIdx.x * NPB;

#pragma unroll
    for (int p = 0; p < F4PT; ++p) {
        int e = p * 256 + t;
        int row = e / (IN / 4);
        int c4 = e % (IN / 4);
        long gr = base + row;
        if (gr >= N_NODES) gr = N_NODES - 1;
        float4 v = *reinterpret_cast<const float4*>(&x[gr * IN + c4 * 4]);
        float* d = &sx[row * STRIDE + c4 * 4];
        d[0] = v.x; d[1] = v.y; d[2] = v.z; d[3] = v.w;
    }
    __syncthreads();

    int w = t >> 6, lane = t & 63;
    int s = __builtin_amdgcn_readfirstlane(w % SPLIT);
    int grp = __builtin_amdgcn_readfirstlane(w / SPLIT);
    int r = grp * 64 + lane;
    long n = base + r;

    float acc[16];
#pragma unroll
    for (int j = 0; j < 16; ++j) acc[j] = 0.f;

    const float* Ws = W + s * 16;
#pragma unroll 8
    for (int k = 0; k < IN; ++k) {
        float xv = sx[r * STRIDE + k];
        const float* Wr = Ws + k * OUT;
#pragma unroll
        for (int j = 0; j < 16; ++j) acc[j] = fmaf(xv, Wr[j], acc[j]);
    }

    if (n < N_NODES) {
        unsigned u[8];
#pragma unroll
        for (int k = 0; k < 8; ++k)
            u[k] = f2bf(acc[2 * k]) | (f2bf(acc[2 * k + 1]) << 16);
        uint4* dst = reinterpret_cast<uint4*>(&h[n * OUT + s * 16]);
        dst[0] = make_uint4(u[0], u[1], u[2], u[3]);
        dst[1] = make_uint4(u[4], u[5], u[6], u[7]);
    }

    float ps = 0.f, pd = 0.f;
#pragma unroll
    for (int j = 0; j < 16; ++j) {
        ps = fmaf(acc[j], asrc[s * 16 + j], ps);
        pd = fmaf(acc[j], adst[s * 16 + j], pd);
    }
    if (HEADS == SPLIT) {
        if (n < N_NODES) {
            als[n * HEADS + s] = ps;
            ald[n * HEADS + s] = pd;
        }
    } else {
        __syncthreads();
        sx[r * 2 + s] = ps;
        sx[NPB * 2 + r * 2 + s] = pd;
        __syncthreads();
        if (t < NPB) {
            long nn = base + t;
            if (nn < N_NODES) {
                als[nn] = sx[t * 2] + sx[t * 2 + 1];
                ald[nn] = sx[NPB * 2 + t * 2] + sx[NPB * 2 + t * 2 + 1];
            }
        }
    }
}

// XCD-aligned node mapping for agg: XCD k (blockIdx&7) processes dst range k.
static __device__ __forceinline__ int agg_node(int blk, int wid) {
    return (blk & 7) * PART_SZ + (blk >> 3) * 4 + wid;
}

// ---------------- aggregation, H=4 C=16, bf16 payload, uint4 lanes ----------------
// bf16 row = 128 B = 8 lanes x uint4 -> q=lane>>3 gives 8 edges in flight.
__global__ __launch_bounds__(256) void agg_h4(const int* __restrict__ cnt, const int* __restrict__ srcs,
                                              const unsigned short* __restrict__ h, const float* __restrict__ als,
                                              const float* __restrict__ ald, const float* __restrict__ bias,
                                              float* __restrict__ g, int do_relu) {
    const uint4* hrow = reinterpret_cast<const uint4*>(h);   // 8 uint4 per 64-ch row
    int wid = threadIdx.x >> 6, lane = threadIdx.x & 63;
    int n = agg_node(blockIdx.x, wid);
    if (n >= N_NODES) return;
    int q = lane >> 3, cc = lane & 7;
    int hd = cc >> 1;
    float ad = ald[n * 4 + hd];
    int deg = cnt[n]; if (deg > CAP) deg = CAP;   // deg >= 1 (self-loop)
    int e0 = n * CAP, e1 = e0 + deg;
    float a0 = 0.f, a1 = 0.f, a2 = 0.f, a3 = 0.f, a4 = 0.f, a5 = 0.f, a6 = 0.f, a7 = 0.f;
    float den = 0.f;

    int idxA = e0 + q; if (idxA >= e1) idxA = e1 - 1;
    int sA = srcs[idxA];
    float alA = als[sA * 4 + hd];
    uint4 hvA = hrow[(long)sA * 8 + cc];
    bool mA = (e0 + q) < e1;

    for (int e = e0; e < e1; e += 8) {
        int eB = e + 8;
        int sB = sA; float alB = alA; uint4 hvB = hvA; bool mB = mA;
        if (eB < e1) {                    // wave-uniform branch
            int idxB = eB + q; if (idxB >= e1) idxB = e1 - 1;
            sB = srcs[idxB];
            alB = als[sB * 4 + hd];
            hvB = hrow[(long)sB * 8 + cc];
            mB = (eB + q) < e1;
        }
        float w = mA ? __expf(lrelu(alA + ad)) : 0.f;
        den += w;
        a0 = fmaf(w, bf_lo(hvA.x), a0);
        a1 = fmaf(w, bf_hi(hvA.x), a1);
        a2 = fmaf(w, bf_lo(hvA.y), a2);
        a3 = fmaf(w, bf_hi(hvA.y), a3);
        a4 = fmaf(w, bf_lo(hvA.z), a4);
        a5 = fmaf(w, bf_hi(hvA.z), a5);
        a6 = fmaf(w, bf_lo(hvA.w), a6);
        a7 = fmaf(w, bf_hi(hvA.w), a7);
        sA = sB; alA = alB; hvA = hvB; mA = mB;
    }

#pragma unroll
    for (int d = 8; d <= 32; d <<= 1) {
        a0 += __shfl_xor(a0, d); a1 += __shfl_xor(a1, d);
        a2 += __shfl_xor(a2, d); a3 += __shfl_xor(a3, d);
        a4 += __shfl_xor(a4, d); a5 += __shfl_xor(a5, d);
        a6 += __shfl_xor(a6, d); a7 += __shfl_xor(a7, d);
        den += __shfl_xor(den, d);
    }
    if (q == 0) {
        float4 b0 = *reinterpret_cast<const float4*>(&bias[cc * 8]);
        float4 b1 = *reinterpret_cast<const float4*>(&bias[cc * 8 + 4]);
        float inv = 1.f / den;
        float4 o0, o1;
        o0.x = fmaf(a0, inv, b0.x); o0.y = fmaf(a1, inv, b0.y);
        o0.z = fmaf(a2, inv, b0.z); o0.w = fmaf(a3, inv, b0.w);
        o1.x = fmaf(a4, inv, b1.x); o1.y = fmaf(a5, inv, b1.y);
        o1.z = fmaf(a6, inv, b1.z); o1.w = fmaf(a7, inv, b1.w);
        if (do_relu) {
            o0.x = fmaxf(o0.x, 0.f); o0.y = fmaxf(o0.y, 0.f);
            o0.z = fmaxf(o0.z, 0.f); o0.w = fmaxf(o0.w, 0.f);
            o1.x = fmaxf(o1.x, 0.f); o1.y = fmaxf(o1.y, 0.f);
            o1.z = fmaxf(o1.z, 0.f); o1.w = fmaxf(o1.w, 0.f);
        }
        *reinterpret_cast<float4*>(&g[(long)n * 64 + cc * 8]) = o0;
        *reinterpret_cast<float4*>(&g[(long)n * 64 + cc * 8 + 4]) = o1;
    }
}

// ---------------- aggregation, H=1 C=32, bf16 payload, uint4 lanes ----------------
// 32-ch bf16 row = 64 B = 4 lanes x uint4 -> q=lane>>2 gives 16 edges in flight.
__global__ __launch_bounds__(256) void agg_h1(const int* __restrict__ cnt, const int* __restrict__ srcs,
                                              const unsigned short* __restrict__ h3, const float* __restrict__ als,
                                              const float* __restrict__ ald, const float* __restrict__ bias,
                                              float* __restrict__ out) {
    const uint4* hrow = reinterpret_cast<const uint4*>(h3);  // 4 uint4 per 32-ch row
    int wid = threadIdx.x >> 6, lane = threadIdx.x & 63;
    int n = agg_node(blockIdx.x, wid);
    if (n >= N_NODES) return;
    int q = lane >> 2, cc = lane & 3;
    float ad = ald[n];
    int deg = cnt[n]; if (deg > CAP) deg = CAP;
    int e0 = n * CAP, e1 = e0 + deg;
    float a0 = 0.f, a1 = 0.f, a2 = 0.f, a3 = 0.f, a4 = 0.f, a5 = 0.f, a6 = 0.f, a7 = 0.f;
    float den = 0.f;

    int idxA = e0 + q; if (idxA >= e1) idxA = e1 - 1;
    int sA = srcs[idxA];
    float alA = als[sA];
    uint4 hvA = hrow[(long)sA * 4 + cc];
    bool mA = (e0 + q) < e1;

    for (int e = e0; e < e1; e += 16) {
        int eB = e + 16;
        int sB = sA; float alB = alA; uint4 hvB = hvA; bool mB = mA;
        if (eB < e1) {
            int idxB = eB + q; if (idxB >= e1) idxB = e1 - 1;
            sB = srcs[idxB];
            alB = als[sB];
            hvB = hrow[(long)sB * 4 + cc];
            mB = (eB + q) < e1;
        }
        float w = mA ? __expf(lrelu(alA + ad)) : 0.f;
        den += w;
        a0 = fmaf(w, bf_lo(hvA.x), a0);
        a1 = fmaf(w, bf_hi(hvA.x), a1);
        a2 = fmaf(w, bf_lo(hvA.y), a2);
        a3 = fmaf(w, bf_hi(hvA.y), a3);
        a4 = fmaf(w, bf_lo(hvA.z), a4);
        a5 = fmaf(w, bf_hi(hvA.z), a5);
        a6 = fmaf(w, bf_lo(hvA.w), a6);
        a7 = fmaf(w, bf_hi(hvA.w), a7);
        sA = sB; alA = alB; hvA = hvB; mA = mB;
    }

#pragma unroll
    for (int d = 4; d <= 32; d <<= 1) {
        a0 += __shfl_xor(a0, d); a1 += __shfl_xor(a1, d);
        a2 += __shfl_xor(a2, d); a3 += __shfl_xor(a3, d);
        a4 += __shfl_xor(a4, d); a5 += __shfl_xor(a5, d);
        a6 += __shfl_xor(a6, d); a7 += __shfl_xor(a7, d);
        den += __shfl_xor(den, d);
    }
    if (q == 0) {
        float4 b0 = *reinterpret_cast<const float4*>(&bias[cc * 8]);
        float4 b1 = *reinterpret_cast<const float4*>(&bias[cc * 8 + 4]);
        float inv = 1.f / den;
        float4 o0, o1;
        o0.x = fmaf(a0, inv, b0.x); o0.y = fmaf(a1, inv, b0.y);
        o0.z = fmaf(a2, inv, b0.z); o0.w = fmaf(a3, inv, b0.w);
        o1.x = fmaf(a4, inv, b1.x); o1.y = fmaf(a5, inv, b1.y);
        o1.z = fmaf(a6, inv, b1.z); o1.w = fmaf(a7, inv, b1.w);
        *reinterpret_cast<float4*>(&out[(long)n * 32 + cc * 8]) = o0;
        *reinterpret_cast<float4*>(&out[(long)n * 32 + cc * 8 + 4]) = o1;
    }
}

extern "C" void kernel_launch(void* const* d_in, const int* in_sizes, int n_in,
                              void* d_out, int out_size, void* d_ws, size_t ws_size,
                              hipStream_t stream) {
    (void)in_sizes; (void)n_in; (void)out_size; (void)ws_size;
    const float* x   = (const float*)d_in[0];
    const int*   ei  = (const int*)d_in[1];
    const float* W1  = (const float*)d_in[2];
    const float* as1 = (const float*)d_in[3];
    const float* ad1 = (const float*)d_in[4];
    const float* b1  = (const float*)d_in[5];
    const float* W2  = (const float*)d_in[6];
    const float* as2 = (const float*)d_in[7];
    const float* ad2 = (const float*)d_in[8];
    const float* b2  = (const float*)d_in[9];
    const float* W3  = (const float*)d_in[10];
    const float* as3 = (const float*)d_in[11];
    const float* ad3 = (const float*)d_in[12];
    const float* b3  = (const float*)d_in[13];
    float* out = (float*)d_out;

    char* w = (char*)d_ws;
    auto alloc = [&](size_t bytes) {
        void* p = (void*)w;
        w += (bytes + 255) & ~(size_t)255;
        return p;
    };
    int*            cnt   = (int*)alloc((size_t)N_NODES * 4);
    int*            tails = (int*)alloc((size_t)256 * 4);             // 8 stripes x 32-int pad (128 B/line)
    int*            srcs  = (int*)alloc((size_t)N_NODES * CAP * 4);   // 19.2 MB
    unsigned short* h     = (unsigned short*)alloc((size_t)N_NODES * 64 * 2);  // bf16, 12.8 MB
    float*          g     = (float*)alloc((size_t)N_NODES * 64 * 4);  // 25.6 MB
    float*          als   = (float*)alloc((size_t)N_NODES * 4 * 4);
    float*          ald   = (float*)alloc((size_t)N_NODES * 4 * 4);
    // staging (8 MB) aliases g: consumed by bucket_fill before agg_h4 first writes g.
    unsigned*       stage = (unsigned*)g;

    hipMemsetAsync(cnt, 0, (size_t)N_NODES * 4, stream);
    hipMemsetAsync(tails, 0, (size_t)256 * 4, stream);

    int g64  = (N_NODES + 63) / 64;    // 1563
    int g128 = (N_NODES + 127) / 128;  // 782
    int gAgg = ((N_NODES + 3) / 4 + 7) & ~7;   // 25000 -> mult of 8
    int gBuild = ((E_TOT + EPB - 1) / EPB + 7) & ~7;  // 1664 blocks, mult of 8

    bucket_build<<<gBuild, 256, 0, stream>>>(ei, tails, stage);
    bucket_fill<<<2048, 256, 0, stream>>>(tails, stage, cnt, srcs);

    // layer 1: x[100000,128] @ W1[128,64], H=4
    gemm_al<128, 64, 4, 64><<<g64, 256, 0, stream>>>(x, W1, as1, ad1, h, als, ald);
    agg_h4<<<gAgg, 256, 0, stream>>>(cnt, srcs, h, als, ald, b1, g, 1);
    // layer 2: g[100000,64] @ W2[64,64], H=4
    gemm_al<64, 64, 4, 64><<<g64, 256, 0, stream>>>(g, W2, as2, ad2, h, als, ald);
    agg_h4<<<gAgg, 256, 0, stream>>>(cnt, srcs, h, als, ald, b2, g, 1);
    // layer 3: g[100000,64] @ W3[64,32], H=1 -> d_out
    gemm_al<64, 32, 1, 128><<<g128, 256, 0, stream>>>(g, W3, as3, ad3, h, als, ald);
    agg_h1<<<gAgg, 256, 0, stream>>>(cnt, srcs, h, als, ald, b3, out);
}

// Round 4
// 367.878 us; speedup vs baseline: 5.0492x; 1.1078x over previous
//
#include <hip/hip_runtime.h>

#define N_NODES 100000
#define N_EDGES 1600000
#define NPART   8
#define PART_SZ (N_NODES / NPART)   // 12500 (agg node mapping)
#define CAP 48                      // bucket capacity; degree ~ Poisson(16), P(>=48) ~ 1e-9
#define BSH  10                     // nodes per fill bin = 1024 (node-exclusive block ownership)
#define NBIN 98                     // ceil(100000 / 1024)
#define SCAP2 4096                  // per-(bin,stripe) staging cap: mean 2048, sigma 45 -> +45 sigma
#define SSH2 12                     // log2(SCAP2)
#define EPB  2048                   // edges per build block

static __device__ __forceinline__ float lrelu(float z) { return z > 0.f ? z : 0.2f * z; }

// bf16 round-to-nearest-even pack / unpack (values are finite, no NaN handling)
static __device__ __forceinline__ unsigned f2bf(float f) {
    unsigned u = __float_as_uint(f);
    u += 0x7fffu + ((u >> 16) & 1u);
    return u >> 16;
}
static __device__ __forceinline__ float bf_lo(unsigned v) { return __uint_as_float(v << 16); }
static __device__ __forceinline__ float bf_hi(unsigned v) { return __uint_as_float(v & 0xffff0000u); }

// ---------------- phase A: single-pass edge binning at 1024-node granularity ----------------
// Round-14 pathology: fill's srcs lines were dirtied by blocks on MULTIPLE XCDs; the
// non-coherent per-XCD L2s each wrote back partial sectors -> WRITE_SIZE 65 MB vs 19.6 MB
// logical, 67.7 us. Fix: bin at 1024-node granularity so phase B gets NODE-EXCLUSIVE
// blocks (single-L2 dirty lines by construction, no XCD-mapping assumption).
// Self-loops no longer flow through staging (deterministic slot-0 in fill) -> the
// sequential-dst skew hazard (round-13 bug) is gone entirely. No LDS bins storage:
// each thread keeps its 8 (bin,slot,payload) in registers; one block-level reservation
// per bin (76K atomics on 784 padded counters), then direct stores to staging.
__global__ __launch_bounds__(256) void bucket_build(const int* __restrict__ ei, int* __restrict__ tails,
                                                    unsigned* __restrict__ stage) {
    __shared__ int lcnt[NBIN];
    __shared__ int lbase[NBIN];
    int tid = threadIdx.x;
    if (tid < NBIN) lcnt[tid] = 0;
    __syncthreads();

    int stripe = blockIdx.x & 7;
    int e0 = blockIdx.x * EPB;
    int binv[EPB / 256];
    int slotv[EPB / 256];
    unsigned vv[EPB / 256];
#pragma unroll
    for (int k = 0; k < EPB / 256; ++k) {
        int t = e0 + k * 256 + tid;
        binv[k] = -1;
        if (t < N_EDGES) {
            int d = __builtin_nontemporal_load(ei + N_EDGES + t);
            int s = __builtin_nontemporal_load(ei + t);
            int b = d >> BSH;
            vv[k] = ((unsigned)(d & ((1 << BSH) - 1)) << 17) | (unsigned)s;  // dloc 10b | src 17b
            slotv[k] = atomicAdd(&lcnt[b], 1);
            binv[k] = b;
        }
    }
    __syncthreads();

    if (tid < NBIN) lbase[tid] = atomicAdd(&tails[stripe * 128 + tid], lcnt[tid]);
    __syncthreads();

#pragma unroll
    for (int k = 0; k < EPB / 256; ++k) {
        if (binv[k] >= 0) {
            int pos = lbase[binv[k]] + slotv[k];
            if (pos < SCAP2)
                stage[((((unsigned)binv[k] << 3) | (unsigned)stripe) << SSH2) + (unsigned)pos] = vv[k];
        }
    }
}

// ---------------- phase B: node-exclusive bucket assembly, LDS counters only ----------------
// One 1024-thread block per 1024-node bin: reads its 8 stripe-sublists (contiguous, NT),
// assigns slots via LDS atomics (zero global atomics), writes srcs into lines owned by
// exactly this block -> writeback = touched sectors, once. cnt written coalesced at the
// end (no cnt memset dispatch needed). Self-loop = slot 0, deterministic.
__global__ __launch_bounds__(1024) void bucket_fill(const int* __restrict__ tails, const unsigned* __restrict__ stage,
                                                    int* __restrict__ cnt, int* __restrict__ srcs) {
    __shared__ int lc[1 << BSH];
    int tid = threadIdx.x;
    int bin = blockIdx.x;
    int base = bin << BSH;
    int nn = N_NODES - base; if (nn > (1 << BSH)) nn = 1 << BSH;
    if (tid < nn) {
        lc[tid] = 1;                           // self-loop occupies slot 0
        srcs[(base + tid) * CAP] = base + tid;
    }
    __syncthreads();

    for (int st = 0; st < 8; ++st) {
        int len = tails[st * 128 + bin];
        if (len > SCAP2) len = SCAP2;
        const unsigned* sl = stage + ((((unsigned)bin << 3) | (unsigned)st) << SSH2);
        for (int i = tid; i < len; i += 1024) {
            unsigned v = __builtin_nontemporal_load(sl + i);
            int dloc = (int)(v >> 17);
            int s = (int)(v & 0x1FFFFu);
            int slot = atomicAdd(&lc[dloc], 1);
            if (slot < CAP) srcs[(base + dloc) * CAP + slot] = s;
        }
    }
    __syncthreads();
    if (tid < nn) cnt[base + tid] = lc[tid];   // agg clamps deg > CAP
}

// ---------------- fused GEMM + attention logits (wave-sliced, scalar W path) ----------------
// readfirstlane forces the W address chain into SGPRs -> s_load per k-row (round-6 win).
// h written as bf16 (round-9 win: halves gather traffic downstream).
template <int IN, int OUT, int HEADS, int NPB>
__global__ __launch_bounds__(256) void gemm_al(const float* __restrict__ x, const float* __restrict__ W,
                                               const float* __restrict__ asrc, const float* __restrict__ adst,
                                               unsigned short* __restrict__ h, float* __restrict__ als,
                                               float* __restrict__ ald) {
    constexpr int SPLIT = OUT / 16;
    constexpr int STRIDE = IN + 1;
    constexpr int F4PT = NPB * (IN / 4) / 256;
    __shared__ float sx[NPB * STRIDE];
    int t = threadIdx.x;
    long base = (long)blockIdx.x * NPB;

#pragma unroll
    for (int p = 0; p < F4PT; ++p) {
        int e = p * 256 + t;
        int row = e / (IN / 4);
        int c4 = e % (IN / 4);
        long gr = base + row;
        if (gr >= N_NODES) gr = N_NODES - 1;
        float4 v = *reinterpret_cast<const float4*>(&x[gr * IN + c4 * 4]);
        float* d = &sx[row * STRIDE + c4 * 4];
        d[0] = v.x; d[1] = v.y; d[2] = v.z; d[3] = v.w;
    }
    __syncthreads();

    int w = t >> 6, lane = t & 63;
    int s = __builtin_amdgcn_readfirstlane(w % SPLIT);
    int grp = __builtin_amdgcn_readfirstlane(w / SPLIT);
    int r = grp * 64 + lane;
    long n = base + r;

    float acc[16];
#pragma unroll
    for (int j = 0; j < 16; ++j) acc[j] = 0.f;

    const float* Ws = W + s * 16;
#pragma unroll 8
    for (int k = 0; k < IN; ++k) {
        float xv = sx[r * STRIDE + k];
        const float* Wr = Ws + k * OUT;
#pragma unroll
        for (int j = 0; j < 16; ++j) acc[j] = fmaf(xv, Wr[j], acc[j]);
    }

    if (n < N_NODES) {
        unsigned u[8];
#pragma unroll
        for (int k = 0; k < 8; ++k)
            u[k] = f2bf(acc[2 * k]) | (f2bf(acc[2 * k + 1]) << 16);
        uint4* dst = reinterpret_cast<uint4*>(&h[n * OUT + s * 16]);
        dst[0] = make_uint4(u[0], u[1], u[2], u[3]);
        dst[1] = make_uint4(u[4], u[5], u[6], u[7]);
    }

    float ps = 0.f, pd = 0.f;
#pragma unroll
    for (int j = 0; j < 16; ++j) {
        ps = fmaf(acc[j], asrc[s * 16 + j], ps);
        pd = fmaf(acc[j], adst[s * 16 + j], pd);
    }
    if (HEADS == SPLIT) {
        if (n < N_NODES) {
            als[n * HEADS + s] = ps;
            ald[n * HEADS + s] = pd;
        }
    } else {
        __syncthreads();
        sx[r * 2 + s] = ps;
        sx[NPB * 2 + r * 2 + s] = pd;
        __syncthreads();
        if (t < NPB) {
            long nn = base + t;
            if (nn < N_NODES) {
                als[nn] = sx[t * 2] + sx[t * 2 + 1];
                ald[nn] = sx[NPB * 2 + t * 2] + sx[NPB * 2 + t * 2 + 1];
            }
        }
    }
}

// XCD-aligned node mapping for agg: XCD k (blockIdx&7) processes dst range k.
static __device__ __forceinline__ int agg_node(int blk, int wid) {
    return (blk & 7) * PART_SZ + (blk >> 3) * 4 + wid;
}

// ---------------- aggregation, H=4 C=16, bf16 payload, uint4 lanes ----------------
// bf16 row = 128 B = 8 lanes x uint4 -> q=lane>>3 gives 8 edges in flight.
__global__ __launch_bounds__(256) void agg_h4(const int* __restrict__ cnt, const int* __restrict__ srcs,
                                              const unsigned short* __restrict__ h, const float* __restrict__ als,
                                              const float* __restrict__ ald, const float* __restrict__ bias,
                                              float* __restrict__ g, int do_relu) {
    const uint4* hrow = reinterpret_cast<const uint4*>(h);   // 8 uint4 per 64-ch row
    int wid = threadIdx.x >> 6, lane = threadIdx.x & 63;
    int n = agg_node(blockIdx.x, wid);
    if (n >= N_NODES) return;
    int q = lane >> 3, cc = lane & 7;
    int hd = cc >> 1;
    float ad = ald[n * 4 + hd];
    int deg = cnt[n]; if (deg > CAP) deg = CAP;   // deg >= 1 (self-loop)
    int e0 = n * CAP, e1 = e0 + deg;
    float a0 = 0.f, a1 = 0.f, a2 = 0.f, a3 = 0.f, a4 = 0.f, a5 = 0.f, a6 = 0.f, a7 = 0.f;
    float den = 0.f;

    int idxA = e0 + q; if (idxA >= e1) idxA = e1 - 1;
    int sA = srcs[idxA];
    float alA = als[sA * 4 + hd];
    uint4 hvA = hrow[(long)sA * 8 + cc];
    bool mA = (e0 + q) < e1;

    for (int e = e0; e < e1; e += 8) {
        int eB = e + 8;
        int sB = sA; float alB = alA; uint4 hvB = hvA; bool mB = mA;
        if (eB < e1) {                    // wave-uniform branch
            int idxB = eB + q; if (idxB >= e1) idxB = e1 - 1;
            sB = srcs[idxB];
            alB = als[sB * 4 + hd];
            hvB = hrow[(long)sB * 8 + cc];
            mB = (eB + q) < e1;
        }
        float w = mA ? __expf(lrelu(alA + ad)) : 0.f;
        den += w;
        a0 = fmaf(w, bf_lo(hvA.x), a0);
        a1 = fmaf(w, bf_hi(hvA.x), a1);
        a2 = fmaf(w, bf_lo(hvA.y), a2);
        a3 = fmaf(w, bf_hi(hvA.y), a3);
        a4 = fmaf(w, bf_lo(hvA.z), a4);
        a5 = fmaf(w, bf_hi(hvA.z), a5);
        a6 = fmaf(w, bf_lo(hvA.w), a6);
        a7 = fmaf(w, bf_hi(hvA.w), a7);
        sA = sB; alA = alB; hvA = hvB; mA = mB;
    }

#pragma unroll
    for (int d = 8; d <= 32; d <<= 1) {
        a0 += __shfl_xor(a0, d); a1 += __shfl_xor(a1, d);
        a2 += __shfl_xor(a2, d); a3 += __shfl_xor(a3, d);
        a4 += __shfl_xor(a4, d); a5 += __shfl_xor(a5, d);
        a6 += __shfl_xor(a6, d); a7 += __shfl_xor(a7, d);
        den += __shfl_xor(den, d);
    }
    if (q == 0) {
        float4 b0 = *reinterpret_cast<const float4*>(&bias[cc * 8]);
        float4 b1 = *reinterpret_cast<const float4*>(&bias[cc * 8 + 4]);
        float inv = 1.f / den;
        float4 o0, o1;
        o0.x = fmaf(a0, inv, b0.x); o0.y = fmaf(a1, inv, b0.y);
        o0.z = fmaf(a2, inv, b0.z); o0.w = fmaf(a3, inv, b0.w);
        o1.x = fmaf(a4, inv, b1.x); o1.y = fmaf(a5, inv, b1.y);
        o1.z = fmaf(a6, inv, b1.z); o1.w = fmaf(a7, inv, b1.w);
        if (do_relu) {
            o0.x = fmaxf(o0.x, 0.f); o0.y = fmaxf(o0.y, 0.f);
            o0.z = fmaxf(o0.z, 0.f); o0.w = fmaxf(o0.w, 0.f);
            o1.x = fmaxf(o1.x, 0.f); o1.y = fmaxf(o1.y, 0.f);
            o1.z = fmaxf(o1.z, 0.f); o1.w = fmaxf(o1.w, 0.f);
        }
        *reinterpret_cast<float4*>(&g[(long)n * 64 + cc * 8]) = o0;
        *reinterpret_cast<float4*>(&g[(long)n * 64 + cc * 8 + 4]) = o1;
    }
}

// ---------------- aggregation, H=1 C=32, bf16 payload, uint4 lanes ----------------
// 32-ch bf16 row = 64 B = 4 lanes x uint4 -> q=lane>>2 gives 16 edges in flight.
__global__ __launch_bounds__(256) void agg_h1(const int* __restrict__ cnt, const int* __restrict__ srcs,
                                              const unsigned short* __restrict__ h3, const float* __restrict__ als,
                                              const float* __restrict__ ald, const float* __restrict__ bias,
                                              float* __restrict__ out) {
    const uint4* hrow = reinterpret_cast<const uint4*>(h3);  // 4 uint4 per 32-ch row
    int wid = threadIdx.x >> 6, lane = threadIdx.x & 63;
    int n = agg_node(blockIdx.x, wid);
    if (n >= N_NODES) return;
    int q = lane >> 2, cc = lane & 3;
    float ad = ald[n];
    int deg = cnt[n]; if (deg > CAP) deg = CAP;
    int e0 = n * CAP, e1 = e0 + deg;
    float a0 = 0.f, a1 = 0.f, a2 = 0.f, a3 = 0.f, a4 = 0.f, a5 = 0.f, a6 = 0.f, a7 = 0.f;
    float den = 0.f;

    int idxA = e0 + q; if (idxA >= e1) idxA = e1 - 1;
    int sA = srcs[idxA];
    float alA = als[sA];
    uint4 hvA = hrow[(long)sA * 4 + cc];
    bool mA = (e0 + q) < e1;

    for (int e = e0; e < e1; e += 16) {
        int eB = e + 16;
        int sB = sA; float alB = alA; uint4 hvB = hvA; bool mB = mA;
        if (eB < e1) {
            int idxB = eB + q; if (idxB >= e1) idxB = e1 - 1;
            sB = srcs[idxB];
            alB = als[sB];
            hvB = hrow[(long)sB * 4 + cc];
            mB = (eB + q) < e1;
        }
        float w = mA ? __expf(lrelu(alA + ad)) : 0.f;
        den += w;
        a0 = fmaf(w, bf_lo(hvA.x), a0);
        a1 = fmaf(w, bf_hi(hvA.x), a1);
        a2 = fmaf(w, bf_lo(hvA.y), a2);
        a3 = fmaf(w, bf_hi(hvA.y), a3);
        a4 = fmaf(w, bf_lo(hvA.z), a4);
        a5 = fmaf(w, bf_hi(hvA.z), a5);
        a6 = fmaf(w, bf_lo(hvA.w), a6);
        a7 = fmaf(w, bf_hi(hvA.w), a7);
        sA = sB; alA = alB; hvA = hvB; mA = mB;
    }

#pragma unroll
    for (int d = 4; d <= 32; d <<= 1) {
        a0 += __shfl_xor(a0, d); a1 += __shfl_xor(a1, d);
        a2 += __shfl_xor(a2, d); a3 += __shfl_xor(a3, d);
        a4 += __shfl_xor(a4, d); a5 += __shfl_xor(a5, d);
        a6 += __shfl_xor(a6, d); a7 += __shfl_xor(a7, d);
        den += __shfl_xor(den, d);
    }
    if (q == 0) {
        float4 b0 = *reinterpret_cast<const float4*>(&bias[cc * 8]);
        float4 b1 = *reinterpret_cast<const float4*>(&bias[cc * 8 + 4]);
        float inv = 1.f / den;
        float4 o0, o1;
        o0.x = fmaf(a0, inv, b0.x); o0.y = fmaf(a1, inv, b0.y);
        o0.z = fmaf(a2, inv, b0.z); o0.w = fmaf(a3, inv, b0.w);
        o1.x = fmaf(a4, inv, b1.x); o1.y = fmaf(a5, inv, b1.y);
        o1.z = fmaf(a6, inv, b1.z); o1.w = fmaf(a7, inv, b1.w);
        *reinterpret_cast<float4*>(&out[(long)n * 32 + cc * 8]) = o0;
        *reinterpret_cast<float4*>(&out[(long)n * 32 + cc * 8 + 4]) = o1;
    }
}

extern "C" void kernel_launch(void* const* d_in, const int* in_sizes, int n_in,
                              void* d_out, int out_size, void* d_ws, size_t ws_size,
                              hipStream_t stream) {
    (void)in_sizes; (void)n_in; (void)out_size; (void)ws_size;
    const float* x   = (const float*)d_in[0];
    const int*   ei  = (const int*)d_in[1];
    const float* W1  = (const float*)d_in[2];
    const float* as1 = (const float*)d_in[3];
    const float* ad1 = (const float*)d_in[4];
    const float* b1  = (const float*)d_in[5];
    const float* W2  = (const float*)d_in[6];
    const float* as2 = (const float*)d_in[7];
    const float* ad2 = (const float*)d_in[8];
    const float* b2  = (const float*)d_in[9];
    const float* W3  = (const float*)d_in[10];
    const float* as3 = (const float*)d_in[11];
    const float* ad3 = (const float*)d_in[12];
    const float* b3  = (const float*)d_in[13];
    float* out = (float*)d_out;

    char* w = (char*)d_ws;
    auto alloc = [&](size_t bytes) {
        void* p = (void*)w;
        w += (bytes + 255) & ~(size_t)255;
        return p;
    };
    int*            cnt   = (int*)alloc((size_t)N_NODES * 4);
    int*            tails = (int*)alloc((size_t)1024 * 4);            // 8 stripes x 128-int pad
    int*            srcs  = (int*)alloc((size_t)N_NODES * CAP * 4);   // 19.2 MB
    unsigned short* h     = (unsigned short*)alloc((size_t)N_NODES * 64 * 2);  // bf16, 12.8 MB
    float*          g     = (float*)alloc((size_t)N_NODES * 64 * 4);  // 25.6 MB
    float*          als   = (float*)alloc((size_t)N_NODES * 4 * 4);
    float*          ald   = (float*)alloc((size_t)N_NODES * 4 * 4);
    // staging (12.85 MB) aliases g: consumed by bucket_fill before agg_h4 first writes g.
    unsigned*       stage = (unsigned*)g;

    hipMemsetAsync(tails, 0, (size_t)1024 * 4, stream);   // cnt memset no longer needed

    int g64  = (N_NODES + 63) / 64;    // 1563
    int g128 = (N_NODES + 127) / 128;  // 782
    int gAgg = ((N_NODES + 3) / 4 + 7) & ~7;   // 25000 -> mult of 8
    int gBuild = (N_EDGES + EPB - 1) / EPB;    // 782 (self-loops not staged)

    bucket_build<<<gBuild, 256, 0, stream>>>(ei, tails, stage);
    bucket_fill<<<NBIN, 1024, 0, stream>>>(tails, stage, cnt, srcs);

    // layer 1: x[100000,128] @ W1[128,64], H=4
    gemm_al<128, 64, 4, 64><<<g64, 256, 0, stream>>>(x, W1, as1, ad1, h, als, ald);
    agg_h4<<<gAgg, 256, 0, stream>>>(cnt, srcs, h, als, ald, b1, g, 1);
    // layer 2: g[100000,64] @ W2[64,64], H=4
    gemm_al<64, 64, 4, 64><<<g64, 256, 0, stream>>>(g, W2, as2, ad2, h, als, ald);
    agg_h4<<<gAgg, 256, 0, stream>>>(cnt, srcs, h, als, ald, b2, g, 1);
    // layer 3: g[100000,64] @ W3[64,32], H=1 -> d_out
    gemm_al<64, 32, 1, 128><<<g128, 256, 0, stream>>>(g, W3, as3, ad3, h, als, ald);
    agg_h1<<<gAgg, 256, 0, stream>>>(cnt, srcs, h, als, ald, b3, out);
}

// Round 5
// 354.321 us; speedup vs baseline: 5.2424x; 1.0383x over previous
//
#include <hip/hip_runtime.h>

#define N_NODES 100000
#define N_EDGES 1600000
#define NPART   8
#define PART_SZ (N_NODES / NPART)   // 12500 (agg node mapping)
#define CAP 48                      // bucket capacity; degree ~ Poisson(16), P(>=48) ~ 1e-9
#define BSH  10                     // nodes per fill bin = 1024 (node-exclusive block ownership)
#define NBIN 98                     // ceil(100000 / 1024)
#define SCAP2 4096                  // per-(bin,stripe) staging cap: mean 2048, sigma 45 -> +45 sigma
#define SSH2 12                     // log2(SCAP2)
#define EPB  2048                   // edges per build block

static __device__ __forceinline__ float lrelu(float z) { return z > 0.f ? z : 0.2f * z; }

// bf16 round-to-nearest-even pack / unpack (values are finite, no NaN handling)
static __device__ __forceinline__ unsigned f2bf(float f) {
    unsigned u = __float_as_uint(f);
    u += 0x7fffu + ((u >> 16) & 1u);
    return u >> 16;
}
static __device__ __forceinline__ float bf_lo(unsigned v) { return __uint_as_float(v << 16); }
static __device__ __forceinline__ float bf_hi(unsigned v) { return __uint_as_float(v & 0xffff0000u); }

// ---------------- phase A: single-pass edge binning at 1024-node granularity ----------------
// (round-15: validated — bucket phase now ~25 us total, fill write-amp gone)
__global__ __launch_bounds__(256) void bucket_build(const int* __restrict__ ei, int* __restrict__ tails,
                                                    unsigned* __restrict__ stage) {
    __shared__ int lcnt[NBIN];
    __shared__ int lbase[NBIN];
    int tid = threadIdx.x;
    if (tid < NBIN) lcnt[tid] = 0;
    __syncthreads();

    int stripe = blockIdx.x & 7;
    int e0 = blockIdx.x * EPB;
    int binv[EPB / 256];
    int slotv[EPB / 256];
    unsigned vv[EPB / 256];
#pragma unroll
    for (int k = 0; k < EPB / 256; ++k) {
        int t = e0 + k * 256 + tid;
        binv[k] = -1;
        if (t < N_EDGES) {
            int d = __builtin_nontemporal_load(ei + N_EDGES + t);
            int s = __builtin_nontemporal_load(ei + t);
            int b = d >> BSH;
            vv[k] = ((unsigned)(d & ((1 << BSH) - 1)) << 17) | (unsigned)s;  // dloc 10b | src 17b
            slotv[k] = atomicAdd(&lcnt[b], 1);
            binv[k] = b;
        }
    }
    __syncthreads();

    if (tid < NBIN) lbase[tid] = atomicAdd(&tails[stripe * 128 + tid], lcnt[tid]);
    __syncthreads();

#pragma unroll
    for (int k = 0; k < EPB / 256; ++k) {
        if (binv[k] >= 0) {
            int pos = lbase[binv[k]] + slotv[k];
            if (pos < SCAP2)
                stage[((((unsigned)binv[k] << 3) | (unsigned)stripe) << SSH2) + (unsigned)pos] = vv[k];
        }
    }
}

// ---------------- phase B: node-exclusive bucket assembly, LDS counters only ----------------
__global__ __launch_bounds__(1024) void bucket_fill(const int* __restrict__ tails, const unsigned* __restrict__ stage,
                                                    int* __restrict__ cnt, int* __restrict__ srcs) {
    __shared__ int lc[1 << BSH];
    int tid = threadIdx.x;
    int bin = blockIdx.x;
    int base = bin << BSH;
    int nn = N_NODES - base; if (nn > (1 << BSH)) nn = 1 << BSH;
    if (tid < nn) {
        lc[tid] = 1;                           // self-loop occupies slot 0
        srcs[(base + tid) * CAP] = base + tid;
    }
    __syncthreads();

    for (int st = 0; st < 8; ++st) {
        int len = tails[st * 128 + bin];
        if (len > SCAP2) len = SCAP2;
        const unsigned* sl = stage + ((((unsigned)bin << 3) | (unsigned)st) << SSH2);
        for (int i = tid; i < len; i += 1024) {
            unsigned v = __builtin_nontemporal_load(sl + i);
            int dloc = (int)(v >> 17);
            int s = (int)(v & 0x1FFFFu);
            int slot = atomicAdd(&lc[dloc], 1);
            if (slot < CAP) srcs[(base + dloc) * CAP + slot] = s;
        }
    }
    __syncthreads();
    if (tid < nn) cnt[base + tid] = lc[tid];   // agg clamps deg > CAP
}

// ---------------- fused GEMM + attention logits (wave-sliced, scalar W path) ----------------
template <int IN, int OUT, int HEADS, int NPB>
__global__ __launch_bounds__(256) void gemm_al(const float* __restrict__ x, const float* __restrict__ W,
                                               const float* __restrict__ asrc, const float* __restrict__ adst,
                                               unsigned short* __restrict__ h, float* __restrict__ als,
                                               float* __restrict__ ald) {
    constexpr int SPLIT = OUT / 16;
    constexpr int STRIDE = IN + 1;
    constexpr int F4PT = NPB * (IN / 4) / 256;
    __shared__ float sx[NPB * STRIDE];
    int t = threadIdx.x;
    long base = (long)blockIdx.x * NPB;

#pragma unroll
    for (int p = 0; p < F4PT; ++p) {
        int e = p * 256 + t;
        int row = e / (IN / 4);
        int c4 = e % (IN / 4);
        long gr = base + row;
        if (gr >= N_NODES) gr = N_NODES - 1;
        float4 v = *reinterpret_cast<const float4*>(&x[gr * IN + c4 * 4]);
        float* d = &sx[row * STRIDE + c4 * 4];
        d[0] = v.x; d[1] = v.y; d[2] = v.z; d[3] = v.w;
    }
    __syncthreads();

    int w = t >> 6, lane = t & 63;
    int s = __builtin_amdgcn_readfirstlane(w % SPLIT);
    int grp = __builtin_amdgcn_readfirstlane(w / SPLIT);
    int r = grp * 64 + lane;
    long n = base + r;

    float acc[16];
#pragma unroll
    for (int j = 0; j < 16; ++j) acc[j] = 0.f;

    const float* Ws = W + s * 16;
#pragma unroll 8
    for (int k = 0; k < IN; ++k) {
        float xv = sx[r * STRIDE + k];
        const float* Wr = Ws + k * OUT;
#pragma unroll
        for (int j = 0; j < 16; ++j) acc[j] = fmaf(xv, Wr[j], acc[j]);
    }

    if (n < N_NODES) {
        unsigned u[8];
#pragma unroll
        for (int k = 0; k < 8; ++k)
            u[k] = f2bf(acc[2 * k]) | (f2bf(acc[2 * k + 1]) << 16);
        uint4* dst = reinterpret_cast<uint4*>(&h[n * OUT + s * 16]);
        dst[0] = make_uint4(u[0], u[1], u[2], u[3]);
        dst[1] = make_uint4(u[4], u[5], u[6], u[7]);
    }

    float ps = 0.f, pd = 0.f;
#pragma unroll
    for (int j = 0; j < 16; ++j) {
        ps = fmaf(acc[j], asrc[s * 16 + j], ps);
        pd = fmaf(acc[j], adst[s * 16 + j], pd);
    }
    if (HEADS == SPLIT) {
        if (n < N_NODES) {
            als[n * HEADS + s] = ps;
            ald[n * HEADS + s] = pd;
        }
    } else {
        __syncthreads();
        sx[r * 2 + s] = ps;
        sx[NPB * 2 + r * 2 + s] = pd;
        __syncthreads();
        if (t < NPB) {
            long nn = base + t;
            if (nn < N_NODES) {
                als[nn] = sx[t * 2] + sx[t * 2 + 1];
                ald[nn] = sx[NPB * 2 + t * 2] + sx[NPB * 2 + t * 2 + 1];
            }
        }
    }
}

// XCD-aligned node mapping for agg: XCD k (blockIdx&7) processes dst range k.
static __device__ __forceinline__ int agg_node(int blk, int wid) {
    return (blk & 7) * PART_SZ + (blk >> 3) * 4 + wid;
}

// ---------------- aggregation, H=4 C=16, bf16 payload, uint4 lanes ----------------
// Round-15 pathology: in-loop chain srcs[idx] -> {als,hrow} is 2 dependent levels
// (~200 + ~500 cy) issued 1 iter ahead; compute covers ~350 cy -> 31% HBM + 55% VALU,
// neither saturated. Fix: the bucket is only 192 B -> ONE coalesced lane-per-edge load
// before the loop; in-loop src comes from __shfl (register). Prefetch chain is now a
// single memory level, issued a full iteration early.
__global__ __launch_bounds__(256) void agg_h4(const int* __restrict__ cnt, const int* __restrict__ srcs,
                                              const unsigned short* __restrict__ h, const float* __restrict__ als,
                                              const float* __restrict__ ald, const float* __restrict__ bias,
                                              float* __restrict__ g, int do_relu) {
    const uint4* hrow = reinterpret_cast<const uint4*>(h);   // 8 uint4 per 64-ch row
    int wid = threadIdx.x >> 6, lane = threadIdx.x & 63;
    int n = agg_node(blockIdx.x, wid);
    if (n >= N_NODES) return;
    int q = lane >> 3, cc = lane & 7;
    int hd = cc >> 1;
    float ad = ald[n * 4 + hd];
    int deg = cnt[n]; if (deg > CAP) deg = CAP;   // deg >= 1 (self-loop)
    // whole bucket, one coalesced load: lane l holds src of edge l
    int sl = srcs[n * CAP + (lane < deg ? lane : deg - 1)];
    int nit = (deg + 7) >> 3;

    float a0 = 0.f, a1 = 0.f, a2 = 0.f, a3 = 0.f, a4 = 0.f, a5 = 0.f, a6 = 0.f, a7 = 0.f;
    float den = 0.f;

    int sA = __shfl(sl, q < deg ? q : deg - 1);
    float alA = als[sA * 4 + hd];
    uint4 hvA = hrow[(long)sA * 8 + cc];

    for (int t = 0; t < nit; ++t) {
        int eB = (t + 1) * 8 + q;
        int sB = __shfl(sl, eB < deg ? eB : deg - 1);
        float alB = alA; uint4 hvB = hvA;
        if (t + 1 < nit) {                 // wave-uniform branch
            alB = als[sB * 4 + hd];
            hvB = hrow[(long)sB * 8 + cc];
        }
        float w = (t * 8 + q) < deg ? __expf(lrelu(alA + ad)) : 0.f;
        den += w;
        a0 = fmaf(w, bf_lo(hvA.x), a0);
        a1 = fmaf(w, bf_hi(hvA.x), a1);
        a2 = fmaf(w, bf_lo(hvA.y), a2);
        a3 = fmaf(w, bf_hi(hvA.y), a3);
        a4 = fmaf(w, bf_lo(hvA.z), a4);
        a5 = fmaf(w, bf_hi(hvA.z), a5);
        a6 = fmaf(w, bf_lo(hvA.w), a6);
        a7 = fmaf(w, bf_hi(hvA.w), a7);
        sA = sB; alA = alB; hvA = hvB;
    }

#pragma unroll
    for (int d = 8; d <= 32; d <<= 1) {
        a0 += __shfl_xor(a0, d); a1 += __shfl_xor(a1, d);
        a2 += __shfl_xor(a2, d); a3 += __shfl_xor(a3, d);
        a4 += __shfl_xor(a4, d); a5 += __shfl_xor(a5, d);
        a6 += __shfl_xor(a6, d); a7 += __shfl_xor(a7, d);
        den += __shfl_xor(den, d);
    }
    if (q == 0) {
        float4 b0 = *reinterpret_cast<const float4*>(&bias[cc * 8]);
        float4 b1 = *reinterpret_cast<const float4*>(&bias[cc * 8 + 4]);
        float inv = 1.f / den;
        float4 o0, o1;
        o0.x = fmaf(a0, inv, b0.x); o0.y = fmaf(a1, inv, b0.y);
        o0.z = fmaf(a2, inv, b0.z); o0.w = fmaf(a3, inv, b0.w);
        o1.x = fmaf(a4, inv, b1.x); o1.y = fmaf(a5, inv, b1.y);
        o1.z = fmaf(a6, inv, b1.z); o1.w = fmaf(a7, inv, b1.w);
        if (do_relu) {
            o0.x = fmaxf(o0.x, 0.f); o0.y = fmaxf(o0.y, 0.f);
            o0.z = fmaxf(o0.z, 0.f); o0.w = fmaxf(o0.w, 0.f);
            o1.x = fmaxf(o1.x, 0.f); o1.y = fmaxf(o1.y, 0.f);
            o1.z = fmaxf(o1.z, 0.f); o1.w = fmaxf(o1.w, 0.f);
        }
        *reinterpret_cast<float4*>(&g[(long)n * 64 + cc * 8]) = o0;
        *reinterpret_cast<float4*>(&g[(long)n * 64 + cc * 8 + 4]) = o1;
    }
}

// ---------------- aggregation, H=1 C=32, bf16 payload, uint4 lanes ----------------
// Same register-bucket restructure; 16 edges in flight (q=lane>>2).
__global__ __launch_bounds__(256) void agg_h1(const int* __restrict__ cnt, const int* __restrict__ srcs,
                                              const unsigned short* __restrict__ h3, const float* __restrict__ als,
                                              const float* __restrict__ ald, const float* __restrict__ bias,
                                              float* __restrict__ out) {
    const uint4* hrow = reinterpret_cast<const uint4*>(h3);  // 4 uint4 per 32-ch row
    int wid = threadIdx.x >> 6, lane = threadIdx.x & 63;
    int n = agg_node(blockIdx.x, wid);
    if (n >= N_NODES) return;
    int q = lane >> 2, cc = lane & 3;
    float ad = ald[n];
    int deg = cnt[n]; if (deg > CAP) deg = CAP;
    int sl = srcs[n * CAP + (lane < deg ? lane : deg - 1)];
    int nit = (deg + 15) >> 4;

    float a0 = 0.f, a1 = 0.f, a2 = 0.f, a3 = 0.f, a4 = 0.f, a5 = 0.f, a6 = 0.f, a7 = 0.f;
    float den = 0.f;

    int sA = __shfl(sl, q < deg ? q : deg - 1);
    float alA = als[sA];
    uint4 hvA = hrow[(long)sA * 4 + cc];

    for (int t = 0; t < nit; ++t) {
        int eB = (t + 1) * 16 + q;
        int sB = __shfl(sl, eB < deg ? eB : deg - 1);
        float alB = alA; uint4 hvB = hvA;
        if (t + 1 < nit) {                 // wave-uniform branch
            alB = als[sB];
            hvB = hrow[(long)sB * 4 + cc];
        }
        float w = (t * 16 + q) < deg ? __expf(lrelu(alA + ad)) : 0.f;
        den += w;
        a0 = fmaf(w, bf_lo(hvA.x), a0);
        a1 = fmaf(w, bf_hi(hvA.x), a1);
        a2 = fmaf(w, bf_lo(hvA.y), a2);
        a3 = fmaf(w, bf_hi(hvA.y), a3);
        a4 = fmaf(w, bf_lo(hvA.z), a4);
        a5 = fmaf(w, bf_hi(hvA.z), a5);
        a6 = fmaf(w, bf_lo(hvA.w), a6);
        a7 = fmaf(w, bf_hi(hvA.w), a7);
        sA = sB; alA = alB; hvA = hvB;
    }

#pragma unroll
    for (int d = 4; d <= 32; d <<= 1) {
        a0 += __shfl_xor(a0, d); a1 += __shfl_xor(a1, d);
        a2 += __shfl_xor(a2, d); a3 += __shfl_xor(a3, d);
        a4 += __shfl_xor(a4, d); a5 += __shfl_xor(a5, d);
        a6 += __shfl_xor(a6, d); a7 += __shfl_xor(a7, d);
        den += __shfl_xor(den, d);
    }
    if (q == 0) {
        float4 b0 = *reinterpret_cast<const float4*>(&bias[cc * 8]);
        float4 b1 = *reinterpret_cast<const float4*>(&bias[cc * 8 + 4]);
        float inv = 1.f / den;
        float4 o0, o1;
        o0.x = fmaf(a0, inv, b0.x); o0.y = fmaf(a1, inv, b0.y);
        o0.z = fmaf(a2, inv, b0.z); o0.w = fmaf(a3, inv, b0.w);
        o1.x = fmaf(a4, inv, b1.x); o1.y = fmaf(a5, inv, b1.y);
        o1.z = fmaf(a6, inv, b1.z); o1.w = fmaf(a7, inv, b1.w);
        *reinterpret_cast<float4*>(&out[(long)n * 32 + cc * 8]) = o0;
        *reinterpret_cast<float4*>(&out[(long)n * 32 + cc * 8 + 4]) = o1;
    }
}

extern "C" void kernel_launch(void* const* d_in, const int* in_sizes, int n_in,
                              void* d_out, int out_size, void* d_ws, size_t ws_size,
                              hipStream_t stream) {
    (void)in_sizes; (void)n_in; (void)out_size; (void)ws_size;
    const float* x   = (const float*)d_in[0];
    const int*   ei  = (const int*)d_in[1];
    const float* W1  = (const float*)d_in[2];
    const float* as1 = (const float*)d_in[3];
    const float* ad1 = (const float*)d_in[4];
    const float* b1  = (const float*)d_in[5];
    const float* W2  = (const float*)d_in[6];
    const float* as2 = (const float*)d_in[7];
    const float* ad2 = (const float*)d_in[8];
    const float* b2  = (const float*)d_in[9];
    const float* W3  = (const float*)d_in[10];
    const float* as3 = (const float*)d_in[11];
    const float* ad3 = (const float*)d_in[12];
    const float* b3  = (const float*)d_in[13];
    float* out = (float*)d_out;

    char* w = (char*)d_ws;
    auto alloc = [&](size_t bytes) {
        void* p = (void*)w;
        w += (bytes + 255) & ~(size_t)255;
        return p;
    };
    int*            cnt   = (int*)alloc((size_t)N_NODES * 4);
    int*            tails = (int*)alloc((size_t)1024 * 4);            // 8 stripes x 128-int pad
    int*            srcs  = (int*)alloc((size_t)N_NODES * CAP * 4);   // 19.2 MB
    unsigned short* h     = (unsigned short*)alloc((size_t)N_NODES * 64 * 2);  // bf16, 12.8 MB
    float*          g     = (float*)alloc((size_t)N_NODES * 64 * 4);  // 25.6 MB
    float*          als   = (float*)alloc((size_t)N_NODES * 4 * 4);
    float*          ald   = (float*)alloc((size_t)N_NODES * 4 * 4);
    // staging (12.85 MB) aliases g: consumed by bucket_fill before agg_h4 first writes g.
    unsigned*       stage = (unsigned*)g;

    hipMemsetAsync(tails, 0, (size_t)1024 * 4, stream);   // cnt memset no longer needed

    int g64  = (N_NODES + 63) / 64;    // 1563
    int g128 = (N_NODES + 127) / 128;  // 782
    int gAgg = ((N_NODES + 3) / 4 + 7) & ~7;   // 25000 -> mult of 8
    int gBuild = (N_EDGES + EPB - 1) / EPB;    // 782 (self-loops not staged)

    bucket_build<<<gBuild, 256, 0, stream>>>(ei, tails, stage);
    bucket_fill<<<NBIN, 1024, 0, stream>>>(tails, stage, cnt, srcs);

    // layer 1: x[100000,128] @ W1[128,64], H=4
    gemm_al<128, 64, 4, 64><<<g64, 256, 0, stream>>>(x, W1, as1, ad1, h, als, ald);
    agg_h4<<<gAgg, 256, 0, stream>>>(cnt, srcs, h, als, ald, b1, g, 1);
    // layer 2: g[100000,64] @ W2[64,64], H=4
    gemm_al<64, 64, 4, 64><<<g64, 256, 0, stream>>>(g, W2, as2, ad2, h, als, ald);
    agg_h4<<<gAgg, 256, 0, stream>>>(cnt, srcs, h, als, ald, b2, g, 1);
    // layer 3: g[100000,64] @ W3[64,32], H=1 -> d_out
    gemm_al<64, 32, 1, 128><<<g128, 256, 0, stream>>>(g, W3, as3, ad3, h, als, ald);
    agg_h1<<<gAgg, 256, 0, stream>>>(cnt, srcs, h, als, ald, b3, out);
}